// Round 2
// baseline (576.578 us; speedup 1.0000x reference)
//
#include <hip/hip_runtime.h>
#include <math.h>

#define TT   8192
#define HH   768
#define FF   3072
#define NEXP 8
#define NP   16384          // T*K pairs
#define BM   128
#define MAXT 135            // ceil(NP/BM) + NEXP - 1
#define ESTR (FF*HH)        // per-expert weight stride (elements)

typedef unsigned short u16;
typedef __attribute__((ext_vector_type(8))) short bf16x8;
typedef __attribute__((ext_vector_type(4))) float f32x4;

__device__ __forceinline__ u16 f2b(float f) {
  unsigned u = __float_as_uint(f);
  unsigned r = (u + 0x7FFFu + ((u >> 16) & 1u)) >> 16;   // RNE
  return (u16)r;
}

__device__ __forceinline__ float gelu_exact(float v) {
  return 0.5f * v * (1.0f + erff(v * 0.70710678118654752f));
}

__device__ __forceinline__ void gll16(const void* g, void* l) {
  __builtin_amdgcn_global_load_lds(
      (const __attribute__((address_space(1))) void*)g,
      (__attribute__((address_space(3))) void*)l, 16, 0, 0);
}

// ---------------- routing ----------------
// hdr layout (ints): [0..7] counts, [8..15] cursors, [16..23] offs, [24] total,
// [32..191] tile_e, [192..351] tile_m, [352..16735] ptok, [16736..33119] pwt(f32)

__global__ void route_zero(int* hdr) {
  int i = blockIdx.x * 64 + threadIdx.x;
  if (i < 32) hdr[i] = 0;
}

__global__ void route_count(const int* __restrict__ te, int* __restrict__ hdr) {
  int i = blockIdx.x * 256 + threadIdx.x;
  if (i < NP) atomicAdd(&hdr[te[i]], 1);
}

__global__ void route_plan(int* hdr) {
  if (threadIdx.x == 0 && blockIdx.x == 0) {
    int* counts = hdr;
    int* offs   = hdr + 16;
    int* tile_e = hdr + 32;
    int* tile_m = hdr + 192;
    int run = 0;
    for (int e = 0; e < NEXP; ++e) { offs[e] = run; run += counts[e]; }
    int tt = 0;
    for (int e = 0; e < NEXP; ++e) {
      int nt = (counts[e] + BM - 1) >> 7;
      for (int i = 0; i < nt; ++i) { tile_e[tt] = e; tile_m[tt] = i * BM; ++tt; }
    }
    hdr[24] = tt;
  }
}

__global__ void route_scatter(const int* __restrict__ te, const float* __restrict__ tw,
                              int* __restrict__ hdr) {
  int i = blockIdx.x * 256 + threadIdx.x;
  if (i < NP) {
    int e = te[i];
    int p = atomicAdd(&hdr[8 + e], 1);
    int idx = hdr[16 + e] + p;
    hdr[352 + idx] = i >> 1;                       // token
    ((float*)(hdr + 16736))[idx] = tw[i];          // weight
  }
}

// ---------------- converts ----------------
__global__ void cvt_bf16x4(const float* __restrict__ src, u16* __restrict__ dst, int n4) {
  int i = blockIdx.x * 256 + threadIdx.x;
  if (i < n4) {
    float4 v = ((const float4*)src)[i];
    ushort4 o;
    o.x = f2b(v.x); o.y = f2b(v.y); o.z = f2b(v.z); o.w = f2b(v.w);
    ((ushort4*)dst)[i] = o;
  }
}

// w2 [E][F][H] f32 -> w2t [E][H][F] bf16
__global__ void transpose_w2(const float* __restrict__ w2, u16* __restrict__ w2t) {
  __shared__ u16 t[32][33];
  int e = blockIdx.z;
  int f0 = blockIdx.x * 32, h0 = blockIdx.y * 32;
  int tx = threadIdx.x, ty = threadIdx.y;
  const float* s = w2 + (size_t)e * ESTR;
  u16* d = w2t + (size_t)e * ESTR;
#pragma unroll
  for (int j = 0; j < 4; ++j) {
    int f = f0 + ty + j * 8;
    t[ty + j * 8][tx] = f2b(s[(size_t)f * HH + h0 + tx]);
  }
  __syncthreads();
#pragma unroll
  for (int j = 0; j < 4; ++j) {
    int h = h0 + ty + j * 8;
    d[(size_t)h * FF + f0 + tx] = t[tx][ty + j * 8];
  }
}

__global__ void bias_init(float* __restrict__ out, const float* __restrict__ bias) {
  __shared__ float bs[HH];
  for (int i = threadIdx.x; i < HH; i += 256) bs[i] = bias[i];
  __syncthreads();
  // each block writes 2 full rows
  int row = blockIdx.x * 2;
  float* o = out + (size_t)row * HH;
  for (int i = threadIdx.x; i < 2 * HH; i += 256) o[i] = bs[i >= HH ? i - HH : i];
}

// ---------------- grouped fused GEMM ----------------
// PHASE 1: h[tile] = gelu(Xg @ w1[e].T)   (A gathered, B = w1 bf16 [F][H] == B^T)
// PHASE 2: out[token] += (Hg @ w2[e]) * wt (A = h contiguous, B = w2t bf16 [H][F] == B^T)
template <int PHASE, int KDIM>
__global__ __launch_bounds__(256)
void moe_gemm(const u16* __restrict__ Asrc, const u16* __restrict__ Bsrc,
              u16* __restrict__ Hout, float* __restrict__ Out,
              const int* __restrict__ hdr) {
  const int mt = blockIdx.y;
  if (mt >= hdr[24]) return;
  const int e   = hdr[32 + mt];
  const int m0  = hdr[192 + mt];
  const int cnt = hdr[e];
  const int off = hdr[16 + e];
  const int nt  = blockIdx.x;
  const int* ptok = hdr + 352;
  const float* pwt = (const float*)(hdr + 16736);

  __shared__ u16 Al[BM * 32];
  __shared__ u16 Bl[BM * 32];

  const int tid  = threadIdx.x;
  const int lane = tid & 63;
  const int wave = tid >> 6;
  const int wm = wave >> 1, wn = wave & 1;

  const int r0 = tid >> 2;          // rows 0..63
  const int r1 = r0 + 64;           // rows 64..127
  const int kc = (tid & 3) * 8;

  const u16 *a0, *a1;
  if (PHASE == 1) {
    int g0 = off + m0 + r0; g0 = g0 < NP ? g0 : NP - 1;
    int g1 = off + m0 + r1; g1 = g1 < NP ? g1 : NP - 1;
    a0 = Asrc + (size_t)ptok[g0] * KDIM + kc;
    a1 = Asrc + (size_t)ptok[g1] * KDIM + kc;
  } else {
    a0 = Asrc + ((size_t)mt * BM + r0) * KDIM + kc;
    a1 = Asrc + ((size_t)mt * BM + r1) * KDIM + kc;
  }
  const u16* Bb = Bsrc + (size_t)e * ESTR;
  const u16* b0 = Bb + ((size_t)nt * BM + r0) * KDIM + kc;
  const u16* b1 = Bb + ((size_t)nt * BM + r1) * KDIM + kc;

  u16* lA0 = Al + wave * 512;
  u16* lA1 = Al + 2048 + wave * 512;
  u16* lB0 = Bl + wave * 512;
  u16* lB1 = Bl + 2048 + wave * 512;

  f32x4 acc[4][4] = {};
  const int lr = lane & 15;
  const int lh = (lane >> 4) * 8;

  for (int kk = 0; kk < KDIM; kk += 32) {
    gll16(a0 + kk, lA0);
    gll16(a1 + kk, lA1);
    gll16(b0 + kk, lB0);
    gll16(b1 + kk, lB1);
    __syncthreads();
    bf16x8 af[4], bfr[4];
#pragma unroll
    for (int i = 0; i < 4; ++i)
      af[i] = *(const bf16x8*)&Al[(wm * 64 + i * 16 + lr) * 32 + lh];
#pragma unroll
    for (int i = 0; i < 4; ++i)
      bfr[i] = *(const bf16x8*)&Bl[(wn * 64 + i * 16 + lr) * 32 + lh];
#pragma unroll
    for (int mi = 0; mi < 4; ++mi)
#pragma unroll
      for (int ni = 0; ni < 4; ++ni)
        acc[mi][ni] = __builtin_amdgcn_mfma_f32_16x16x32_bf16(
            af[mi], bfr[ni], acc[mi][ni], 0, 0, 0);
    __syncthreads();
  }

  if (PHASE == 1) {
    u16* hb = Hout + (size_t)mt * BM * FF + (size_t)nt * BM;
#pragma unroll
    for (int mi = 0; mi < 4; ++mi)
#pragma unroll
      for (int ni = 0; ni < 4; ++ni)
#pragma unroll
        for (int j = 0; j < 4; ++j) {
          int rl = wm * 64 + mi * 16 + (lane >> 4) * 4 + j;
          int cl = wn * 64 + ni * 16 + (lane & 15);
          hb[(size_t)rl * FF + cl] = f2b(gelu_exact(acc[mi][ni][j]));
        }
  } else {
#pragma unroll
    for (int mi = 0; mi < 4; ++mi)
#pragma unroll
      for (int ni = 0; ni < 4; ++ni)
#pragma unroll
        for (int j = 0; j < 4; ++j) {
          int rl = wm * 64 + mi * 16 + (lane >> 4) * 4 + j;
          int lrow = m0 + rl;
          if (lrow < cnt) {
            int g = off + lrow;
            int col = nt * BM + wn * 64 + ni * 16 + (lane & 15);
            atomicAdd(&Out[(size_t)ptok[g] * HH + col], acc[mi][ni][j] * pwt[g]);
          }
        }
  }
}

// ---------------- naive fallback (ws too small) ----------------
__global__ void naive_pair(const float* __restrict__ x, const float* __restrict__ tw,
                           const int* __restrict__ te, const float* __restrict__ w1,
                           const float* __restrict__ w2, float* __restrict__ out) {
  __shared__ float xs[HH];
  __shared__ float hb[FF];
  int t = blockIdx.x >> 1, k = blockIdx.x & 1;
  int e = te[t * 2 + k];
  float wt = tw[t * 2 + k];
  for (int i = threadIdx.x; i < HH; i += 256) xs[i] = x[(size_t)t * HH + i];
  __syncthreads();
  const float* W1 = w1 + (size_t)e * ESTR;
  for (int f = threadIdx.x; f < FF; f += 256) {
    float s = 0.f;
    const float* r = W1 + (size_t)f * HH;
    for (int i = 0; i < HH; ++i) s += xs[i] * r[i];
    hb[f] = gelu_exact(s);
  }
  __syncthreads();
  const float* W2 = w2 + (size_t)e * ESTR;
  for (int c = threadIdx.x; c < HH; c += 256) {
    float s = 0.f;
    for (int f = 0; f < FF; ++f) s += hb[f] * W2[(size_t)f * HH + c];
    atomicAdd(&out[(size_t)t * HH + c], s * wt);
  }
}

extern "C" void kernel_launch(void* const* d_in, const int* in_sizes, int n_in,
                              void* d_out, int out_size, void* d_ws, size_t ws_size,
                              hipStream_t stream) {
  const float* x    = (const float*)d_in[0];
  // d_in[1] ("weights") is unused by the reference computation
  const float* topw = (const float*)d_in[2];
  const int*   tope = (const int*)d_in[3];
  const float* w1   = (const float*)d_in[4];
  const float* w2   = (const float*)d_in[5];
  const float* bias = (const float*)d_in[6];
  float* out = (float*)d_out;

  char* ws = (char*)d_ws;
  const size_t HDRB   = 1u << 18;                       // 256 KB header
  const size_t xb_off  = HDRB;
  const size_t xb_sz   = (size_t)TT * HH * 2;
  const size_t w1_off  = xb_off + xb_sz;
  const size_t w1_sz   = (size_t)NEXP * ESTR * 2;
  const size_t w2t_off = w1_off + w1_sz;
  const size_t w2t_sz  = w1_sz;
  const size_t h_off   = w2t_off + w2t_sz;
  const size_t h_sz    = (size_t)MAXT * BM * FF * 2;
  const size_t need    = h_off + h_sz;

  if (ws_size < need) {
    bias_init<<<TT / 2, 256, 0, stream>>>(out, bias);
    naive_pair<<<NP, 256, 0, stream>>>(x, topw, tope, w1, w2, out);
    return;
  }

  int* hdr  = (int*)ws;
  u16* xb   = (u16*)(ws + xb_off);
  u16* w1b  = (u16*)(ws + w1_off);
  u16* w2t  = (u16*)(ws + w2t_off);
  u16* h    = (u16*)(ws + h_off);

  route_zero<<<1, 64, 0, stream>>>(hdr);
  route_count<<<NP / 256, 256, 0, stream>>>(tope, hdr);
  route_plan<<<1, 1, 0, stream>>>(hdr);
  route_scatter<<<NP / 256, 256, 0, stream>>>(tope, topw, hdr);

  cvt_bf16x4<<<TT * HH / 4 / 256, 256, 0, stream>>>(x, xb, TT * HH / 4);
  cvt_bf16x4<<<NEXP * ESTR / 4 / 256, 256, 0, stream>>>(w1, w1b, NEXP * ESTR / 4);
  transpose_w2<<<dim3(FF / 32, HH / 32, NEXP), dim3(32, 8), 0, stream>>>(w2, w2t);
  bias_init<<<TT / 2, 256, 0, stream>>>(out, bias);

  moe_gemm<1, HH><<<dim3(FF / BM, MAXT), 256, 0, stream>>>(xb, w1b, h, nullptr, hdr);
  moe_gemm<2, FF><<<dim3(HH / BM, MAXT), 256, 0, stream>>>(h, w2t, nullptr, out, hdr);
}

// Round 3
// 530.449 us; speedup vs baseline: 1.0870x; 1.0870x over previous
//
#include <hip/hip_runtime.h>
#include <math.h>

#define TT   8192
#define HH   768
#define FF   3072
#define NEXP 8
#define NP   16384          // T*K pairs
#define BM   128
#define MAXT 135            // ceil(NP/BM) + NEXP - 1
#define MTP  136            // padded tile count (divisible by 8; NB%8==0)
#define ESTR (FF*HH)        // per-expert weight stride (elements)

typedef unsigned short u16;
typedef __attribute__((ext_vector_type(8))) short bf16x8;
typedef __attribute__((ext_vector_type(4))) float f32x4;

__device__ __forceinline__ u16 f2b(float f) {
  unsigned u = __float_as_uint(f);
  unsigned r = (u + 0x7FFFu + ((u >> 16) & 1u)) >> 16;   // RNE
  return (u16)r;
}

__device__ __forceinline__ float gelu_exact(float v) {
  return 0.5f * v * (1.0f + erff(v * 0.70710678118654752f));
}

__device__ __forceinline__ void gll16(const void* g, void* l) {
  __builtin_amdgcn_global_load_lds(
      (const __attribute__((address_space(1))) void*)g,
      (__attribute__((address_space(3))) void*)l, 16, 0, 0);
}

// ---------------- routing ----------------
// hdr layout (ints): [0..7] counts, [8..15] cursors, [16..23] offs, [24] total,
// [32..191] tile_e, [192..351] tile_m, [352..16735] ptok, [16736..33119] pwt(f32)

__global__ void route_zero(int* hdr) {
  int i = blockIdx.x * 64 + threadIdx.x;
  if (i < 32) hdr[i] = 0;
}

__global__ void route_count(const int* __restrict__ te, int* __restrict__ hdr) {
  int i = blockIdx.x * 256 + threadIdx.x;
  if (i < NP) atomicAdd(&hdr[te[i]], 1);
}

__global__ void route_plan(int* hdr) {
  if (threadIdx.x == 0 && blockIdx.x == 0) {
    int* counts = hdr;
    int* offs   = hdr + 16;
    int* tile_e = hdr + 32;
    int* tile_m = hdr + 192;
    int run = 0;
    for (int e = 0; e < NEXP; ++e) { offs[e] = run; run += counts[e]; }
    int tt = 0;
    for (int e = 0; e < NEXP; ++e) {
      int nt = (counts[e] + BM - 1) >> 7;
      for (int i = 0; i < nt; ++i) { tile_e[tt] = e; tile_m[tt] = i * BM; ++tt; }
    }
    hdr[24] = tt;
  }
}

__global__ void route_scatter(const int* __restrict__ te, const float* __restrict__ tw,
                              int* __restrict__ hdr) {
  int i = blockIdx.x * 256 + threadIdx.x;
  if (i < NP) {
    int e = te[i];
    int p = atomicAdd(&hdr[8 + e], 1);
    int idx = hdr[16 + e] + p;
    hdr[352 + idx] = i >> 1;                       // token
    ((float*)(hdr + 16736))[idx] = tw[i];          // weight
  }
}

// ---------------- converts ----------------
__global__ void cvt_bf16x4(const float* __restrict__ src, u16* __restrict__ dst, int n4) {
  int i = blockIdx.x * 256 + threadIdx.x;
  if (i < n4) {
    float4 v = ((const float4*)src)[i];
    ushort4 o;
    o.x = f2b(v.x); o.y = f2b(v.y); o.z = f2b(v.z); o.w = f2b(v.w);
    ((ushort4*)dst)[i] = o;
  }
}

// w2 [E][F][H] f32 -> w2t [E][H][F] bf16
__global__ void transpose_w2(const float* __restrict__ w2, u16* __restrict__ w2t) {
  __shared__ u16 t[32][33];
  int e = blockIdx.z;
  int f0 = blockIdx.x * 32, h0 = blockIdx.y * 32;
  int tx = threadIdx.x, ty = threadIdx.y;
  const float* s = w2 + (size_t)e * ESTR;
  u16* d = w2t + (size_t)e * ESTR;
#pragma unroll
  for (int j = 0; j < 4; ++j) {
    int f = f0 + ty + j * 8;
    t[ty + j * 8][tx] = f2b(s[(size_t)f * HH + h0 + tx]);
  }
  __syncthreads();
#pragma unroll
  for (int j = 0; j < 4; ++j) {
    int h = h0 + ty + j * 8;
    d[(size_t)h * FF + f0 + tx] = t[tx][ty + j * 8];
  }
}

__global__ void bias_init(float* __restrict__ out, const float* __restrict__ bias) {
  __shared__ float bs[HH];
  for (int i = threadIdx.x; i < HH; i += 256) bs[i] = bias[i];
  __syncthreads();
  int row = blockIdx.x * 2;
  float* o = out + (size_t)row * HH;
  for (int i = threadIdx.x; i < 2 * HH; i += 256) o[i] = bs[i >= HH ? i - HH : i];
}

// ---------------- grouped fused GEMM ----------------
// PHASE 1: h[tile] = gelu(Xg @ w1[e].T)   (A gathered, B = w1 bf16 [F][H] == B^T)
// PHASE 2: out[token] += (Hg @ w2[e]) * wt (A = h contiguous, B = w2t bf16 [H][F] == B^T)
// Grid: 1-D, NT*MTP blocks. bid -> XCD-contiguous logical id l (bijective,
// NB%8==0), then l -> (supergroup of G M-tiles, nt swept inside) so each XCD's
// L2 keeps G A-tiles + 1 B-panel resident.
template <int PHASE, int KDIM, int NT, int G>
__global__ __launch_bounds__(256)
void moe_gemm(const u16* __restrict__ Asrc, const u16* __restrict__ Bsrc,
              u16* __restrict__ Hout, float* __restrict__ Out,
              const int* __restrict__ hdr) {
  const int nwg = NT * MTP;
  const int bid = blockIdx.x;
  const int l   = (bid & 7) * (nwg >> 3) + (bid >> 3);
  const int sg  = l / (NT * G);
  const int rem = l % (NT * G);
  const int nt  = rem / G;
  const int mt  = sg * G + rem % G;
  if (mt >= hdr[24]) return;

  const int e   = hdr[32 + mt];
  const int m0  = hdr[192 + mt];
  const int cnt = hdr[e];
  const int off = hdr[16 + e];
  const int* ptok = hdr + 352;
  const float* pwt = (const float*)(hdr + 16736);

  __shared__ u16 Al[BM * 32];
  __shared__ u16 Bl[BM * 32];

  const int tid  = threadIdx.x;
  const int lane = tid & 63;
  const int wave = tid >> 6;
  const int wm = wave >> 1, wn = wave & 1;

  const int r0 = tid >> 2;          // rows 0..63
  const int r1 = r0 + 64;           // rows 64..127
  const int kc = (tid & 3) * 8;

  const u16 *a0, *a1;
  if (PHASE == 1) {
    int g0 = off + m0 + r0; g0 = g0 < NP ? g0 : NP - 1;
    int g1 = off + m0 + r1; g1 = g1 < NP ? g1 : NP - 1;
    a0 = Asrc + (size_t)ptok[g0] * KDIM + kc;
    a1 = Asrc + (size_t)ptok[g1] * KDIM + kc;
  } else {
    a0 = Asrc + ((size_t)mt * BM + r0) * KDIM + kc;
    a1 = Asrc + ((size_t)mt * BM + r1) * KDIM + kc;
  }
  const u16* Bb = Bsrc + (size_t)e * ESTR;
  const u16* b0 = Bb + ((size_t)nt * BM + r0) * KDIM + kc;
  const u16* b1 = Bb + ((size_t)nt * BM + r1) * KDIM + kc;

  u16* lA0 = Al + wave * 512;
  u16* lA1 = Al + 2048 + wave * 512;
  u16* lB0 = Bl + wave * 512;
  u16* lB1 = Bl + 2048 + wave * 512;

  f32x4 acc[4][4] = {};
  const int lr = lane & 15;
  const int lh = (lane >> 4) * 8;

  for (int kk = 0; kk < KDIM; kk += 32) {
    gll16(a0 + kk, lA0);
    gll16(a1 + kk, lA1);
    gll16(b0 + kk, lB0);
    gll16(b1 + kk, lB1);
    __syncthreads();
    bf16x8 af[4], bfr[4];
#pragma unroll
    for (int i = 0; i < 4; ++i)
      af[i] = *(const bf16x8*)&Al[(wm * 64 + i * 16 + lr) * 32 + lh];
#pragma unroll
    for (int i = 0; i < 4; ++i)
      bfr[i] = *(const bf16x8*)&Bl[(wn * 64 + i * 16 + lr) * 32 + lh];
#pragma unroll
    for (int mi = 0; mi < 4; ++mi)
#pragma unroll
      for (int ni = 0; ni < 4; ++ni)
        acc[mi][ni] = __builtin_amdgcn_mfma_f32_16x16x32_bf16(
            af[mi], bfr[ni], acc[mi][ni], 0, 0, 0);
    __syncthreads();
  }

  if (PHASE == 1) {
    u16* hb = Hout + (size_t)mt * BM * FF + (size_t)nt * BM;
#pragma unroll
    for (int mi = 0; mi < 4; ++mi)
#pragma unroll
      for (int ni = 0; ni < 4; ++ni)
#pragma unroll
        for (int j = 0; j < 4; ++j) {
          int rl = wm * 64 + mi * 16 + (lane >> 4) * 4 + j;
          int cl = wn * 64 + ni * 16 + (lane & 15);
          hb[(size_t)rl * FF + cl] = f2b(gelu_exact(acc[mi][ni][j]));
        }
  } else {
#pragma unroll
    for (int mi = 0; mi < 4; ++mi)
#pragma unroll
      for (int ni = 0; ni < 4; ++ni)
#pragma unroll
        for (int j = 0; j < 4; ++j) {
          int rl = wm * 64 + mi * 16 + (lane >> 4) * 4 + j;
          int lrow = m0 + rl;
          if (lrow < cnt) {
            int g = off + lrow;
            int col = nt * BM + wn * 64 + ni * 16 + (lane & 15);
            atomicAdd(&Out[(size_t)ptok[g] * HH + col], acc[mi][ni][j] * pwt[g]);
          }
        }
  }
}

// ---------------- naive fallback (ws too small) ----------------
__global__ void naive_pair(const float* __restrict__ x, const float* __restrict__ tw,
                           const int* __restrict__ te, const float* __restrict__ w1,
                           const float* __restrict__ w2, float* __restrict__ out) {
  __shared__ float xs[HH];
  __shared__ float hb[FF];
  int t = blockIdx.x >> 1, k = blockIdx.x & 1;
  int e = te[t * 2 + k];
  float wt = tw[t * 2 + k];
  for (int i = threadIdx.x; i < HH; i += 256) xs[i] = x[(size_t)t * HH + i];
  __syncthreads();
  const float* W1 = w1 + (size_t)e * ESTR;
  for (int f = threadIdx.x; f < FF; f += 256) {
    float s = 0.f;
    const float* r = W1 + (size_t)f * HH;
    for (int i = 0; i < HH; ++i) s += xs[i] * r[i];
    hb[f] = gelu_exact(s);
  }
  __syncthreads();
  const float* W2 = w2 + (size_t)e * ESTR;
  for (int c = threadIdx.x; c < HH; c += 256) {
    float s = 0.f;
    for (int f = 0; f < FF; ++f) s += hb[f] * W2[(size_t)f * HH + c];
    atomicAdd(&out[(size_t)t * HH + c], s * wt);
  }
}

extern "C" void kernel_launch(void* const* d_in, const int* in_sizes, int n_in,
                              void* d_out, int out_size, void* d_ws, size_t ws_size,
                              hipStream_t stream) {
  const float* x    = (const float*)d_in[0];
  // d_in[1] ("weights") is unused by the reference computation
  const float* topw = (const float*)d_in[2];
  const int*   tope = (const int*)d_in[3];
  const float* w1   = (const float*)d_in[4];
  const float* w2   = (const float*)d_in[5];
  const float* bias = (const float*)d_in[6];
  float* out = (float*)d_out;

  char* ws = (char*)d_ws;
  const size_t HDRB   = 1u << 18;                       // 256 KB header
  const size_t xb_off  = HDRB;
  const size_t xb_sz   = (size_t)TT * HH * 2;
  const size_t w1_off  = xb_off + xb_sz;
  const size_t w1_sz   = (size_t)NEXP * ESTR * 2;
  const size_t w2t_off = w1_off + w1_sz;
  const size_t w2t_sz  = w1_sz;
  const size_t h_off   = w2t_off + w2t_sz;
  const size_t h_sz    = (size_t)MAXT * BM * FF * 2;
  const size_t need    = h_off + h_sz;

  if (ws_size < need) {
    bias_init<<<TT / 2, 256, 0, stream>>>(out, bias);
    naive_pair<<<NP, 256, 0, stream>>>(x, topw, tope, w1, w2, out);
    return;
  }

  int* hdr  = (int*)ws;
  u16* xb   = (u16*)(ws + xb_off);
  u16* w1b  = (u16*)(ws + w1_off);
  u16* w2t  = (u16*)(ws + w2t_off);
  u16* h    = (u16*)(ws + h_off);

  route_zero<<<1, 64, 0, stream>>>(hdr);
  route_count<<<NP / 256, 256, 0, stream>>>(tope, hdr);
  route_plan<<<1, 1, 0, stream>>>(hdr);
  route_scatter<<<NP / 256, 256, 0, stream>>>(tope, topw, hdr);

  cvt_bf16x4<<<TT * HH / 4 / 256, 256, 0, stream>>>(x, xb, TT * HH / 4);
  cvt_bf16x4<<<NEXP * ESTR / 4 / 256, 256, 0, stream>>>(w1, w1b, NEXP * ESTR / 4);
  transpose_w2<<<dim3(FF / 32, HH / 32, NEXP), dim3(32, 8), 0, stream>>>(w2, w2t);
  bias_init<<<TT / 2, 256, 0, stream>>>(out, bias);

  // phase 1: NT=24, G=8 (A ws 1.6MB + B panel 0.2MB per XCD L2)
  moe_gemm<1, HH, FF / BM, 8><<<(FF / BM) * MTP, 256, 0, stream>>>(xb, w1b, h, nullptr, hdr);
  // phase 2: NT=6, G=4 (A ws 3MB + B panel 0.77MB per XCD L2)
  moe_gemm<2, FF, HH / BM, 4><<<(HH / BM) * MTP, 256, 0, stream>>>(h, w2t, nullptr, out, hdr);
}